// Round 7
// baseline (431.507 us; speedup 1.0000x reference)
//
#include <hip/hip_runtime.h>

typedef unsigned short u16;
typedef unsigned int   u32;
typedef __bf16 bf16x8 __attribute__((ext_vector_type(8)));
typedef float  f32x4  __attribute__((ext_vector_type(4)));

__device__ __forceinline__ u16 f2bf(float f) {
  u32 u = __float_as_uint(f);
  u32 r = (u + 0x7fffu + ((u >> 16) & 1u)) >> 16;   // RNE
  return (u16)r;
}

typedef const __attribute__((address_space(1))) u32* gp1;
typedef __attribute__((address_space(3))) u32* lp3;
__device__ __forceinline__ void gload16(const void* g, void* l) {
  __builtin_amdgcn_global_load_lds((gp1)g, (lp3)l, 16, 0, 0);
}

__device__ __forceinline__ f32x4 mfma16(bf16x8 a, bf16x8 b, f32x4 c) {
  return __builtin_amdgcn_mfma_f32_16x16x32_bf16(a, b, c, 0, 0, 0);
}

// ---------------- cast fp32 -> bf16, 8 elems/thread ----------------
__global__ __launch_bounds__(256) void cast_bf16(const float* __restrict__ s,
                                                 u16* __restrict__ d, int n8) {
  int i = blockIdx.x * 256 + threadIdx.x;
  if (i >= n8) return;
  const float4* s4 = (const float4*)s;
  float4 a = s4[2 * i], b = s4[2 * i + 1];
  uint4 o;
  o.x = (u32)f2bf(a.x) | ((u32)f2bf(a.y) << 16);
  o.y = (u32)f2bf(a.z) | ((u32)f2bf(a.w) << 16);
  o.z = (u32)f2bf(b.x) | ((u32)f2bf(b.y) << 16);
  o.w = (u32)f2bf(b.z) | ((u32)f2bf(b.w) << 16);
  ((uint4*)d)[i] = o;
}

// ---------------- QKV GEMM: C(8192x2304) = Xb(8192x768) * Wqkv^T ----------------
// Q scaled by 0.125; V stored TRANSPOSED [b,h,d,n]
__global__ __launch_bounds__(256) void gemm_qkv(
    const u16* __restrict__ A, const u16* __restrict__ Bm,
    const float* __restrict__ bias,
    u16* __restrict__ Q, u16* __restrict__ K, u16* __restrict__ V) {
  __shared__ u16 As[128 * 32];
  __shared__ u16 Bs[128 * 32];
  const int tid = threadIdx.x, w = tid >> 6, l = tid & 63;
  const int lr = l & 15, lg = l >> 4;
  const int n0 = blockIdx.x * 128, m0 = blockIdx.y * 128;
  const int wr = (w >> 1) * 64, wc = (w & 1) * 64;
  f32x4 acc[4][4] = {};
  for (int kt = 0; kt < 768; kt += 32) {
    __syncthreads();
    const u16* Ab = A + m0 * 768 + kt;
    const u16* Bb = Bm + n0 * 768 + kt;
#pragma unroll
    for (int i = 0; i < 2; ++i) {
      int c = (i * 4 + w) * 64 + l;
      gload16(Ab + (c >> 2) * 768 + (c & 3) * 8, (char*)As + c * 16);
      gload16(Bb + (c >> 2) * 768 + (c & 3) * 8, (char*)Bs + c * 16);
    }
    __syncthreads();
    bf16x8 af[4], bfr[4];
#pragma unroll
    for (int m = 0; m < 4; ++m)
      af[m] = *(const bf16x8*)&As[(wr + m * 16 + lr) * 32 + lg * 8];
#pragma unroll
    for (int n = 0; n < 4; ++n)
      bfr[n] = *(const bf16x8*)&Bs[(wc + n * 16 + lr) * 32 + lg * 8];
#pragma unroll
    for (int m = 0; m < 4; ++m)
#pragma unroll
      for (int n = 0; n < 4; ++n) acc[m][n] = mfma16(af[m], bfr[n], acc[m][n]);
  }
#pragma unroll
  for (int n = 0; n < 4; ++n) {
    int f = n0 + wc + n * 16 + lr;
    float bv = bias[f];
    int three = f / 768;
    int hd = f - three * 768;
    int h = hd >> 6, dd = hd & 63;
    if (three == 2) {
      // V^T: row = (b*12+h)*64+dd, 4 consecutive tokens per 8B store
#pragma unroll
      for (int m = 0; m < 4; ++m) {
        int row0 = m0 + wr + m * 16 + lg * 4;
        int b2 = row0 >> 11, ns = row0 & 2047;
        ushort4 pk;
        pk.x = f2bf(acc[m][n][0] + bv);
        pk.y = f2bf(acc[m][n][1] + bv);
        pk.z = f2bf(acc[m][n][2] + bv);
        pk.w = f2bf(acc[m][n][3] + bv);
        *(ushort4*)&V[((size_t)(b2 * 12 + h) * 64 + dd) * 2048 + ns] = pk;
      }
    } else {
      u16* dst = (three == 0) ? Q : K;
      float sc = (three == 0) ? 0.125f : 1.0f;
#pragma unroll
      for (int m = 0; m < 4; ++m) {
        int row0 = m0 + wr + m * 16 + lg * 4;
#pragma unroll
        for (int j = 0; j < 4; ++j) {
          int row = row0 + j;
          int b2 = row >> 11, ns = row & 2047;
          float val = (acc[m][n][j] + bv) * sc;
          dst[(((b2 * 12 + h) * 2048 + ns) << 6) + dd] = f2bf(val);
        }
      }
    }
  }
}

// ---------------- flash attention v7: 64 q-rows/block, 16/wave, grid 1536 ----------
// TLP-first: 6 blocks/CU = 24 waves/CU. Swapped QK^T; defer-max; L2-direct K/V.
__global__ __launch_bounds__(256, 6) void attn_kernel(
    const u16* __restrict__ Q, const u16* __restrict__ K,
    const u16* __restrict__ Vt, u16* __restrict__ O) {
  __shared__ u16 Ps[2][64 * 40];   // 80B rows: 16B-aligned frags, odd bank stride
  const int tid = threadIdx.x, w = tid >> 6, l = tid & 63;
  const int lr = l & 15, lg = l >> 4;
  // XCD swizzle: 192 consecutive bi per XCD = 6 whole (b,h) K/V streams (3MB L2)
  int d0i = blockIdx.x;
  int bi = (d0i & 7) * 192 + (d0i >> 3);
  int qt = bi & 31, hh = bi >> 5;
  int h = hh % 12, b = hh / 12;
  const u16* Qp = Q + ((size_t)(b * 12 + h) * 2048 + qt * 64) * 64;
  const u16* Kp = K + (size_t)(b * 12 + h) * 2048 * 64;
  const u16* Vp = Vt + (size_t)(b * 12 + h) * 64 * 2048;   // [d][n]
  u16* Op = O + (size_t)(b * 2048 + qt * 64) * 768 + h * 64;

  // Q fragments (B-operand: col=lr <-> q-row), wave w owns rows [w*16, w*16+16)
  bf16x8 aq[2];
#pragma unroll
  for (int ks = 0; ks < 2; ++ks)
    aq[ks] = *(const bf16x8*)&Qp[(w * 16 + lr) * 64 + ks * 32 + lg * 8];

  f32x4 aO[4] = {};
  float Mx = -1e30f;
  float rsum = 0.0f;

  for (int kt = 0; kt < 64; ++kt) {
    const int kv0 = kt * 32;
    // K fragments (A-operand: row=lr <-> k-row), straight from L2
    bf16x8 ak[2][2];
#pragma unroll
    for (int nt = 0; nt < 2; ++nt)
#pragma unroll
      for (int ks = 0; ks < 2; ++ks)
        ak[nt][ks] = *(const bf16x8*)&Kp[(kv0 + nt * 16 + lr) * 64 + ks * 32 + lg * 8];
    // V fragments (B-operand: row=lr <-> d), from V^T
    bf16x8 av[4];
#pragma unroll
    for (int dt = 0; dt < 4; ++dt)
      av[dt] = *(const bf16x8*)&Vp[(dt * 16 + lr) * 2048 + kv0 + lg * 8];

    // S^T = K·Q^T : lane holds S[q = w*16+lr][k = kv0 + nt*16 + lg*4 + j]
    f32x4 S[2] = {};
    __builtin_amdgcn_s_setprio(1);
#pragma unroll
    for (int ks = 0; ks < 2; ++ks)
#pragma unroll
      for (int nt = 0; nt < 2; ++nt)
        S[nt] = mfma16(ak[nt][ks], aq[ks], S[nt]);
    __builtin_amdgcn_s_setprio(0);

    // defer-max softmax (no cross-lane traffic in steady state)
    float pmax = S[0][0];
#pragma unroll
    for (int nt = 0; nt < 2; ++nt)
#pragma unroll
      for (int j = 0; j < 4; ++j) pmax = fmaxf(pmax, S[nt][j]);
    if (!__all(pmax - Mx <= 8.0f)) {   // rare: full reduce + rescale
      float rm = fmaxf(pmax, __shfl_xor(pmax, 16));
      rm = fmaxf(rm, __shfl_xor(rm, 32));
      float mnew = fmaxf(Mx, rm);
      float sc = __expf(Mx - mnew);
      Mx = mnew;
      rsum *= sc;
      f32x4 scv;
#pragma unroll
      for (int j = 0; j < 4; ++j) scv[j] = __shfl(sc, lg * 4 + j, 16);
#pragma unroll
      for (int dt = 0; dt < 4; ++dt) aO[dt] *= scv;
    }
    char* psb = (char*)Ps[kt & 1];
    {
      int row = w * 16 + lr;
      char* rowb = psb + row * 80;
      float ts = 0.0f;
#pragma unroll
      for (int nt = 0; nt < 2; ++nt) {
        float p0 = __expf(S[nt][0] - Mx);
        float p1 = __expf(S[nt][1] - Mx);
        float p2 = __expf(S[nt][2] - Mx);
        float p3 = __expf(S[nt][3] - Mx);
        ts += (p0 + p1) + (p2 + p3);
        uint2 pk2;
        pk2.x = (u32)f2bf(p0) | ((u32)f2bf(p1) << 16);
        pk2.y = (u32)f2bf(p2) | ((u32)f2bf(p3) << 16);
        *(uint2*)(rowb + nt * 32 + lg * 8) = pk2;
      }
      rsum += ts;
    }

    // P fragment back (A-operand: row=lr <-> q-row, 16B contiguous)
    bf16x8 ap = *(const bf16x8*)(psb + (w * 16 + lr) * 80 + lg * 16);

    // O += P·V
    __builtin_amdgcn_s_setprio(1);
#pragma unroll
    for (int dt = 0; dt < 4; ++dt) aO[dt] = mfma16(ap, av[dt], aO[dt]);
    __builtin_amdgcn_s_setprio(0);
  }

  // L: combine the 4 lane-group partials (lanes sharing lr)
  rsum += __shfl_xor(rsum, 16);
  rsum += __shfl_xor(rsum, 32);
  // epilogue: row (lg*4+j)'s L fetched from lr-space via shfl
  float rinv[4];
#pragma unroll
  for (int j = 0; j < 4; ++j) rinv[j] = 1.0f / __shfl(rsum, lg * 4 + j, 16);
#pragma unroll
  for (int dt = 0; dt < 4; ++dt)
#pragma unroll
    for (int j = 0; j < 4; ++j) {
      int row = w * 16 + lg * 4 + j;
      Op[(size_t)row * 768 + dt * 16 + lr] = f2bf(aO[dt][j] * rinv[j]);
    }
}

// ---------------- out GEMM: C(8192x768) = Ob(8192x768) * Wout^T + b, fp32 out ----------------
__global__ __launch_bounds__(256) void gemm_out(
    const u16* __restrict__ A, const u16* __restrict__ Bm,
    const float* __restrict__ bias, float* __restrict__ C) {
  __shared__ u16 As[128 * 32];
  __shared__ u16 Bs[128 * 32];
  const int tid = threadIdx.x, w = tid >> 6, l = tid & 63;
  const int lr = l & 15, lg = l >> 4;
  const int n0 = blockIdx.x * 128, m0 = blockIdx.y * 128;
  const int wr = (w >> 1) * 64, wc = (w & 1) * 64;
  f32x4 acc[4][4] = {};
  for (int kt = 0; kt < 768; kt += 32) {
    __syncthreads();
    const u16* Ab = A + m0 * 768 + kt;
    const u16* Bb = Bm + n0 * 768 + kt;
#pragma unroll
    for (int i = 0; i < 2; ++i) {
      int c = (i * 4 + w) * 64 + l;
      gload16(Ab + (c >> 2) * 768 + (c & 3) * 8, (char*)As + c * 16);
      gload16(Bb + (c >> 2) * 768 + (c & 3) * 8, (char*)Bs + c * 16);
    }
    __syncthreads();
    bf16x8 af[4], bfr[4];
#pragma unroll
    for (int m = 0; m < 4; ++m)
      af[m] = *(const bf16x8*)&As[(wr + m * 16 + lr) * 32 + lg * 8];
#pragma unroll
    for (int n = 0; n < 4; ++n)
      bfr[n] = *(const bf16x8*)&Bs[(wc + n * 16 + lr) * 32 + lg * 8];
#pragma unroll
    for (int m = 0; m < 4; ++m)
#pragma unroll
      for (int n = 0; n < 4; ++n) acc[m][n] = mfma16(af[m], bfr[n], acc[m][n]);
  }
#pragma unroll
  for (int n = 0; n < 4; ++n) {
    int f = n0 + wc + n * 16 + lr;
    float bv = bias[f];
#pragma unroll
    for (int m = 0; m < 4; ++m) {
      int row0 = m0 + wr + m * 16 + lg * 4;
#pragma unroll
      for (int j = 0; j < 4; ++j) {
        int row = row0 + j;
        C[(size_t)row * 768 + f] = acc[m][n][j] + bv;
      }
    }
  }
}

extern "C" void kernel_launch(void* const* d_in, const int* in_sizes, int n_in,
                              void* d_out, int out_size, void* d_ws, size_t ws_size,
                              hipStream_t stream) {
  const float* x     = (const float*)d_in[0];
  const float* w_qkv = (const float*)d_in[1];
  const float* b_qkv = (const float*)d_in[2];
  const float* w_out = (const float*)d_in[3];
  const float* b_out = (const float*)d_in[4];

  char* ws = (char*)d_ws;
  u16* xb    = (u16*)(ws + 0);
  u16* wqkvb = (u16*)(ws + 12582912);
  u16* wob   = (u16*)(ws + 16121856);
  u16* qb    = (u16*)(ws + 17301504);
  u16* kb    = (u16*)(ws + 29884416);
  u16* vb    = (u16*)(ws + 42467328);   // V^T [b,h,d,n]
  u16* ob    = (u16*)(ws + 55050240);

  cast_bf16<<<786432 / 256, 256, 0, stream>>>(x, xb, 786432);
  cast_bf16<<<221184 / 256, 256, 0, stream>>>(w_qkv, wqkvb, 221184);
  cast_bf16<<<73728 / 256, 256, 0, stream>>>(w_out, wob, 73728);

  gemm_qkv<<<dim3(18, 64), 256, 0, stream>>>(xb, wqkvb, b_qkv, qb, kb, vb);
  attn_kernel<<<1536, 256, 0, stream>>>(qb, kb, vb, ob);
  gemm_out<<<dim3(6, 64), 256, 0, stream>>>(ob, wob, b_out, (float*)d_out);
}

// Round 8
// 182.874 us; speedup vs baseline: 2.3596x; 2.3596x over previous
//
#include <hip/hip_runtime.h>

typedef unsigned short u16;
typedef unsigned int   u32;
typedef __bf16 bf16x8 __attribute__((ext_vector_type(8)));
typedef float  f32x4  __attribute__((ext_vector_type(4)));

__device__ __forceinline__ u16 f2bf(float f) {
  u32 u = __float_as_uint(f);
  u32 r = (u + 0x7fffu + ((u >> 16) & 1u)) >> 16;   // RNE
  return (u16)r;
}

typedef const __attribute__((address_space(1))) u32* gp1;
typedef __attribute__((address_space(3))) u32* lp3;
__device__ __forceinline__ void gload16(const void* g, void* l) {
  __builtin_amdgcn_global_load_lds((gp1)g, (lp3)l, 16, 0, 0);
}

__device__ __forceinline__ f32x4 mfma16(bf16x8 a, bf16x8 b, f32x4 c) {
  return __builtin_amdgcn_mfma_f32_16x16x32_bf16(a, b, c, 0, 0, 0);
}

__device__ __forceinline__ int swz8(int r) { return (r ^ (r >> 3)) & 7; }

// ---------------- cast fp32 -> bf16, 8 elems/thread ----------------
__global__ __launch_bounds__(256) void cast_bf16(const float* __restrict__ s,
                                                 u16* __restrict__ d, int n8) {
  int i = blockIdx.x * 256 + threadIdx.x;
  if (i >= n8) return;
  const float4* s4 = (const float4*)s;
  float4 a = s4[2 * i], b = s4[2 * i + 1];
  uint4 o;
  o.x = (u32)f2bf(a.x) | ((u32)f2bf(a.y) << 16);
  o.y = (u32)f2bf(a.z) | ((u32)f2bf(a.w) << 16);
  o.z = (u32)f2bf(b.x) | ((u32)f2bf(b.y) << 16);
  o.w = (u32)f2bf(b.z) | ((u32)f2bf(b.w) << 16);
  ((uint4*)d)[i] = o;
}

// ---------------- QKV GEMM: C(8192x2304) = Xb(8192x768) * Wqkv^T ----------------
// Q scaled by 0.125; V stored TRANSPOSED [b,h,d,n]
__global__ __launch_bounds__(256) void gemm_qkv(
    const u16* __restrict__ A, const u16* __restrict__ Bm,
    const float* __restrict__ bias,
    u16* __restrict__ Q, u16* __restrict__ K, u16* __restrict__ V) {
  __shared__ u16 As[128 * 32];
  __shared__ u16 Bs[128 * 32];
  const int tid = threadIdx.x, w = tid >> 6, l = tid & 63;
  const int lr = l & 15, lg = l >> 4;
  const int n0 = blockIdx.x * 128, m0 = blockIdx.y * 128;
  const int wr = (w >> 1) * 64, wc = (w & 1) * 64;
  f32x4 acc[4][4] = {};
  for (int kt = 0; kt < 768; kt += 32) {
    __syncthreads();
    const u16* Ab = A + m0 * 768 + kt;
    const u16* Bb = Bm + n0 * 768 + kt;
#pragma unroll
    for (int i = 0; i < 2; ++i) {
      int c = (i * 4 + w) * 64 + l;
      gload16(Ab + (c >> 2) * 768 + (c & 3) * 8, (char*)As + c * 16);
      gload16(Bb + (c >> 2) * 768 + (c & 3) * 8, (char*)Bs + c * 16);
    }
    __syncthreads();
    bf16x8 af[4], bfr[4];
#pragma unroll
    for (int m = 0; m < 4; ++m)
      af[m] = *(const bf16x8*)&As[(wr + m * 16 + lr) * 32 + lg * 8];
#pragma unroll
    for (int n = 0; n < 4; ++n)
      bfr[n] = *(const bf16x8*)&Bs[(wc + n * 16 + lr) * 32 + lg * 8];
#pragma unroll
    for (int m = 0; m < 4; ++m)
#pragma unroll
      for (int n = 0; n < 4; ++n) acc[m][n] = mfma16(af[m], bfr[n], acc[m][n]);
  }
#pragma unroll
  for (int n = 0; n < 4; ++n) {
    int f = n0 + wc + n * 16 + lr;
    float bv = bias[f];
    int three = f / 768;
    int hd = f - three * 768;
    int h = hd >> 6, dd = hd & 63;
    if (three == 2) {
      // V^T: row = (b*12+h)*64+dd, 4 consecutive tokens per 8B store
#pragma unroll
      for (int m = 0; m < 4; ++m) {
        int row0 = m0 + wr + m * 16 + lg * 4;
        int b2 = row0 >> 11, ns = row0 & 2047;
        ushort4 pk;
        pk.x = f2bf(acc[m][n][0] + bv);
        pk.y = f2bf(acc[m][n][1] + bv);
        pk.z = f2bf(acc[m][n][2] + bv);
        pk.w = f2bf(acc[m][n][3] + bv);
        *(ushort4*)&V[((size_t)(b2 * 12 + h) * 64 + dd) * 2048 + ns] = pk;
      }
    } else {
      u16* dst = (three == 0) ? Q : K;
      float sc = (three == 0) ? 0.125f : 1.0f;
#pragma unroll
      for (int m = 0; m < 4; ++m) {
        int row0 = m0 + wr + m * 16 + lg * 4;
#pragma unroll
        for (int j = 0; j < 4; ++j) {
          int row = row0 + j;
          int b2 = row >> 11, ns = row & 2047;
          float val = (acc[m][n][j] + bv) * sc;
          dst[(((b2 * 12 + h) * 2048 + ns) << 6) + dd] = f2bf(val);
        }
      }
    }
  }
}

// ---------------- flash attention v8: LDS-staged K/V (gload_lds), defer-max ------
// 128 q-rows/block (32/wave), KVBLK=64, double-buffered K/V staged once per block.
// Swapped QK^T: lane holds S[q = w*32+mt*16+lr][k = nt*16+lg*4+j].
__global__ __launch_bounds__(256, 3) void attn_kernel(
    const u16* __restrict__ Q, const u16* __restrict__ K,
    const u16* __restrict__ Vt, u16* __restrict__ O) {
  __shared__ u16 Ks[2][64 * 64];   // [kv][d] rows 128B, chunk^swz8(row)
  __shared__ u16 Vs[2][64 * 64];   // [d][kv] rows 128B, chunk^swz8(row)
  __shared__ u16 Ps[128 * 64];     // [q][kv] rows 128B, chunk^swz8(row); wave-private
  const int tid = threadIdx.x, w = tid >> 6, l = tid & 63;
  const int lr = l & 15, lg = l >> 4;
  int d0i = blockIdx.x;
  int bi = (d0i & 7) * 96 + (d0i >> 3);          // XCD swizzle: 6 heads per XCD
  int qt = bi & 15, h = (bi >> 4) % 12, b = bi / 192;
  const u16* Qp = Q + ((size_t)(b * 12 + h) * 2048 + qt * 128) * 64;
  const u16* Kp = K + (size_t)(b * 12 + h) * 2048 * 64;
  const u16* Vp = Vt + (size_t)(b * 12 + h) * 64 * 2048;   // [d][n]
  u16* Op = O + (size_t)(b * 2048 + qt * 128) * 768 + h * 64;

  // Q fragments (B-operand: col=lr <-> q-row)
  bf16x8 aq[2][2];
#pragma unroll
  for (int mt = 0; mt < 2; ++mt)
#pragma unroll
    for (int ks = 0; ks < 2; ++ks)
      aq[mt][ks] = *(const bf16x8*)&Qp[(w * 32 + mt * 16 + lr) * 64 + ks * 32 + lg * 8];

  f32x4 aO[2][4] = {};
  float Mx[2] = {-1e30f, -1e30f};
  float rsum[2] = {0.0f, 0.0f};

  // stage tile kt into buffer buf: K tile [64 kv][64 d], V^T tile [64 d][64 kv]
  // inverse-swizzled SOURCE + linear dest (rule #21); 4 gload_lds per wave
#define STAGE(buf, kt)                                                         \
  do {                                                                         \
    const u16* Kt = Kp + (kt) * 4096;                                          \
    const u16* Vg = Vp + (kt) * 64;                                            \
    _Pragma("unroll") for (int i = 0; i < 2; ++i) {                            \
      int c = i * 256 + tid;                                                   \
      int r = c >> 3, q = c & 7;                                               \
      int qs = (q ^ swz8(r)) << 3;                                             \
      gload16(Kt + r * 64 + qs, (char*)Ks[buf] + c * 16);                      \
      gload16(Vg + r * 2048 + qs, (char*)Vs[buf] + c * 16);                    \
    }                                                                          \
  } while (0)

  STAGE(0, 0);
  __syncthreads();

  for (int kt = 0; kt < 32; ++kt) {
    const int p = kt & 1;
    if (kt < 31) STAGE(p ^ 1, kt + 1);          // prefetch: full iter of cover

    // ---- S^T = K·Q^T from Ks[p] ----
    f32x4 S[2][4] = {};
    __builtin_amdgcn_s_setprio(1);
#pragma unroll
    for (int nt = 0; nt < 4; ++nt) {
      int row = nt * 16 + lr;
      int sw = swz8(row);
#pragma unroll
      for (int ks = 0; ks < 2; ++ks) {
        bf16x8 a = *(const bf16x8*)((char*)Ks[p] + row * 128 +
                                    (((ks * 4 + lg) ^ sw) << 4));
        S[0][nt] = mfma16(a, aq[0][ks], S[0][nt]);
        S[1][nt] = mfma16(a, aq[1][ks], S[1][nt]);
      }
    }
    __builtin_amdgcn_s_setprio(0);

    // ---- defer-max softmax (no cross-lane traffic in steady state) ----
#pragma unroll
    for (int mt = 0; mt < 2; ++mt) {
      float pmax = S[mt][0][0];
#pragma unroll
      for (int nt = 0; nt < 4; ++nt)
#pragma unroll
        for (int j = 0; j < 4; ++j) pmax = fmaxf(pmax, S[mt][nt][j]);
      if (!__all(pmax - Mx[mt] <= 8.0f)) {   // rare: full reduce + rescale
        float rm = fmaxf(pmax, __shfl_xor(pmax, 16));
        rm = fmaxf(rm, __shfl_xor(rm, 32));
        float mnew = fmaxf(Mx[mt], rm);
        float sc = __expf(Mx[mt] - mnew);
        Mx[mt] = mnew;
        rsum[mt] *= sc;
        f32x4 scv;
#pragma unroll
        for (int j = 0; j < 4; ++j) scv[j] = __shfl(sc, lg * 4 + j, 16);
#pragma unroll
        for (int dt = 0; dt < 4; ++dt) aO[mt][dt] *= scv;
      }
      float m = Mx[mt];
      int row = w * 32 + mt * 16 + lr;
      char* rowb = (char*)Ps + row * 128;
      int sw = swz8(row);
      float ts = 0.0f;
#pragma unroll
      for (int nt = 0; nt < 4; ++nt) {
        float p0 = __expf(S[mt][nt][0] - m);
        float p1 = __expf(S[mt][nt][1] - m);
        float p2 = __expf(S[mt][nt][2] - m);
        float p3 = __expf(S[mt][nt][3] - m);
        ts += (p0 + p1) + (p2 + p3);
        uint2 pk2;
        pk2.x = (u32)f2bf(p0) | ((u32)f2bf(p1) << 16);
        pk2.y = (u32)f2bf(p2) | ((u32)f2bf(p3) << 16);
        // kv = nt*16+lg*4 -> chunk cc = nt*2+(lg>>1), half-sel (lg&1)*8
        *(uint2*)(rowb + (((nt * 2 + (lg >> 1)) ^ sw) << 4) + (lg & 1) * 8) = pk2;
      }
      rsum[mt] += ts;
    }

    // ---- O += P·V from Ps (wave-private, same-wave LDS order) and Vs[p] ----
    __builtin_amdgcn_s_setprio(1);
#pragma unroll
    for (int ks = 0; ks < 2; ++ks) {
      bf16x8 ap[2];
#pragma unroll
      for (int mt = 0; mt < 2; ++mt) {
        int row = w * 32 + mt * 16 + lr;
        ap[mt] = *(const bf16x8*)((char*)Ps + row * 128 +
                                  (((ks * 4 + lg) ^ swz8(row)) << 4));
      }
#pragma unroll
      for (int dt = 0; dt < 4; ++dt) {
        int row = dt * 16 + lr;
        bf16x8 bv = *(const bf16x8*)((char*)Vs[p] + row * 128 +
                                     (((ks * 4 + lg) ^ swz8(row)) << 4));
        aO[0][dt] = mfma16(ap[0], bv, aO[0][dt]);
        aO[1][dt] = mfma16(ap[1], bv, aO[1][dt]);
      }
    }
    __builtin_amdgcn_s_setprio(0);

    __syncthreads();   // drains prefetch (had whole iter), guards dbuf WAR
  }

  // L: combine the 4 lane-group partials (lanes sharing lr)
#pragma unroll
  for (int mt = 0; mt < 2; ++mt) {
    rsum[mt] += __shfl_xor(rsum[mt], 16);
    rsum[mt] += __shfl_xor(rsum[mt], 32);
  }
  // epilogue: row (lg*4+j)'s L fetched from lr-space via shfl
#pragma unroll
  for (int mt = 0; mt < 2; ++mt) {
    float rinv[4];
#pragma unroll
    for (int j = 0; j < 4; ++j) rinv[j] = 1.0f / __shfl(rsum[mt], lg * 4 + j, 16);
#pragma unroll
    for (int dt = 0; dt < 4; ++dt)
#pragma unroll
      for (int j = 0; j < 4; ++j) {
        int row = w * 32 + mt * 16 + lg * 4 + j;
        Op[(size_t)row * 768 + dt * 16 + lr] = f2bf(aO[mt][dt][j] * rinv[j]);
      }
  }
}

// ---------------- out GEMM: C(8192x768) = Ob(8192x768) * Wout^T + b, fp32 out ----------------
__global__ __launch_bounds__(256) void gemm_out(
    const u16* __restrict__ A, const u16* __restrict__ Bm,
    const float* __restrict__ bias, float* __restrict__ C) {
  __shared__ u16 As[128 * 32];
  __shared__ u16 Bs[128 * 32];
  const int tid = threadIdx.x, w = tid >> 6, l = tid & 63;
  const int lr = l & 15, lg = l >> 4;
  const int n0 = blockIdx.x * 128, m0 = blockIdx.y * 128;
  const int wr = (w >> 1) * 64, wc = (w & 1) * 64;
  f32x4 acc[4][4] = {};
  for (int kt = 0; kt < 768; kt += 32) {
    __syncthreads();
    const u16* Ab = A + m0 * 768 + kt;
    const u16* Bb = Bm + n0 * 768 + kt;
#pragma unroll
    for (int i = 0; i < 2; ++i) {
      int c = (i * 4 + w) * 64 + l;
      gload16(Ab + (c >> 2) * 768 + (c & 3) * 8, (char*)As + c * 16);
      gload16(Bb + (c >> 2) * 768 + (c & 3) * 8, (char*)Bs + c * 16);
    }
    __syncthreads();
    bf16x8 af[4], bfr[4];
#pragma unroll
    for (int m = 0; m < 4; ++m)
      af[m] = *(const bf16x8*)&As[(wr + m * 16 + lr) * 32 + lg * 8];
#pragma unroll
    for (int n = 0; n < 4; ++n)
      bfr[n] = *(const bf16x8*)&Bs[(wc + n * 16 + lr) * 32 + lg * 8];
#pragma unroll
    for (int m = 0; m < 4; ++m)
#pragma unroll
      for (int n = 0; n < 4; ++n) acc[m][n] = mfma16(af[m], bfr[n], acc[m][n]);
  }
#pragma unroll
  for (int n = 0; n < 4; ++n) {
    int f = n0 + wc + n * 16 + lr;
    float bv = bias[f];
#pragma unroll
    for (int m = 0; m < 4; ++m) {
      int row0 = m0 + wr + m * 16 + lg * 4;
#pragma unroll
      for (int j = 0; j < 4; ++j) {
        int row = row0 + j;
        C[(size_t)row * 768 + f] = acc[m][n][j] + bv;
      }
    }
  }
}

extern "C" void kernel_launch(void* const* d_in, const int* in_sizes, int n_in,
                              void* d_out, int out_size, void* d_ws, size_t ws_size,
                              hipStream_t stream) {
  const float* x     = (const float*)d_in[0];
  const float* w_qkv = (const float*)d_in[1];
  const float* b_qkv = (const float*)d_in[2];
  const float* w_out = (const float*)d_in[3];
  const float* b_out = (const float*)d_in[4];

  char* ws = (char*)d_ws;
  u16* xb    = (u16*)(ws + 0);
  u16* wqkvb = (u16*)(ws + 12582912);
  u16* wob   = (u16*)(ws + 16121856);
  u16* qb    = (u16*)(ws + 17301504);
  u16* kb    = (u16*)(ws + 29884416);
  u16* vb    = (u16*)(ws + 42467328);   // V^T [b,h,d,n]
  u16* ob    = (u16*)(ws + 55050240);

  cast_bf16<<<786432 / 256, 256, 0, stream>>>(x, xb, 786432);
  cast_bf16<<<221184 / 256, 256, 0, stream>>>(w_qkv, wqkvb, 221184);
  cast_bf16<<<73728 / 256, 256, 0, stream>>>(w_out, wob, 73728);

  gemm_qkv<<<dim3(18, 64), 256, 0, stream>>>(xb, wqkvb, b_qkv, qb, kb, vb);
  attn_kernel<<<768, 256, 0, stream>>>(qb, kb, vb, ob);
  gemm_out<<<dim3(6, 64), 256, 0, stream>>>(ob, wob, b_out, (float*)d_out);
}

// Round 10
// 168.941 us; speedup vs baseline: 2.5542x; 1.0825x over previous
//
#include <hip/hip_runtime.h>

typedef unsigned short u16;
typedef unsigned int   u32;
typedef __bf16 bf16x4 __attribute__((ext_vector_type(4)));
typedef __bf16 bf16x8 __attribute__((ext_vector_type(8)));
typedef float  f32x4  __attribute__((ext_vector_type(4)));

__device__ __forceinline__ u16 f2bf(float f) {
  u32 u = __float_as_uint(f);
  u32 r = (u + 0x7fffu + ((u >> 16) & 1u)) >> 16;   // RNE
  return (u16)r;
}

__device__ __forceinline__ float fexp2(float x) {
  return __builtin_amdgcn_exp2f(x);   // bare v_exp_f32
}

typedef const __attribute__((address_space(1))) u32* gp1;
typedef __attribute__((address_space(3))) u32* lp3;
__device__ __forceinline__ void gload16(const void* g, void* l) {
  __builtin_amdgcn_global_load_lds((gp1)g, (lp3)l, 16, 0, 0);
}

__device__ __forceinline__ f32x4 mfma16(bf16x8 a, bf16x8 b, f32x4 c) {
  return __builtin_amdgcn_mfma_f32_16x16x32_bf16(a, b, c, 0, 0, 0);
}

__device__ __forceinline__ int swz8(int r) { return (r ^ (r >> 3)) & 7; }

// ---------------- cast fp32 -> bf16, 8 elems/thread ----------------
__global__ __launch_bounds__(256) void cast_bf16(const float* __restrict__ s,
                                                 u16* __restrict__ d, int n8) {
  int i = blockIdx.x * 256 + threadIdx.x;
  if (i >= n8) return;
  const float4* s4 = (const float4*)s;
  float4 a = s4[2 * i], b = s4[2 * i + 1];
  uint4 o;
  o.x = (u32)f2bf(a.x) | ((u32)f2bf(a.y) << 16);
  o.y = (u32)f2bf(a.z) | ((u32)f2bf(a.w) << 16);
  o.z = (u32)f2bf(b.x) | ((u32)f2bf(b.y) << 16);
  o.w = (u32)f2bf(b.z) | ((u32)f2bf(b.w) << 16);
  ((uint4*)d)[i] = o;
}

// ---------------- QKV GEMM: C(8192x2304) = Xb(8192x768) * Wqkv^T ----------------
// Q scaled by 0.125*log2(e) (exp2-direct softmax); V stored TRANSPOSED [b,h,d,n]
__global__ __launch_bounds__(256) void gemm_qkv(
    const u16* __restrict__ A, const u16* __restrict__ Bm,
    const float* __restrict__ bias,
    u16* __restrict__ Q, u16* __restrict__ K, u16* __restrict__ V) {
  __shared__ u16 As[128 * 32];
  __shared__ u16 Bs[128 * 32];
  const int tid = threadIdx.x, w = tid >> 6, l = tid & 63;
  const int lr = l & 15, lg = l >> 4;
  const int n0 = blockIdx.x * 128, m0 = blockIdx.y * 128;
  const int wr = (w >> 1) * 64, wc = (w & 1) * 64;
  f32x4 acc[4][4] = {};
  for (int kt = 0; kt < 768; kt += 32) {
    __syncthreads();
    const u16* Ab = A + m0 * 768 + kt;
    const u16* Bb = Bm + n0 * 768 + kt;
#pragma unroll
    for (int i = 0; i < 2; ++i) {
      int c = (i * 4 + w) * 64 + l;
      gload16(Ab + (c >> 2) * 768 + (c & 3) * 8, (char*)As + c * 16);
      gload16(Bb + (c >> 2) * 768 + (c & 3) * 8, (char*)Bs + c * 16);
    }
    __syncthreads();
    bf16x8 af[4], bfr[4];
#pragma unroll
    for (int m = 0; m < 4; ++m)
      af[m] = *(const bf16x8*)&As[(wr + m * 16 + lr) * 32 + lg * 8];
#pragma unroll
    for (int n = 0; n < 4; ++n)
      bfr[n] = *(const bf16x8*)&Bs[(wc + n * 16 + lr) * 32 + lg * 8];
#pragma unroll
    for (int m = 0; m < 4; ++m)
#pragma unroll
      for (int n = 0; n < 4; ++n) acc[m][n] = mfma16(af[m], bfr[n], acc[m][n]);
  }
#pragma unroll
  for (int n = 0; n < 4; ++n) {
    int f = n0 + wc + n * 16 + lr;
    float bv = bias[f];
    int three = f / 768;
    int hd = f - three * 768;
    int h = hd >> 6, dd = hd & 63;
    if (three == 2) {
      // V^T: row = (b*12+h)*64+dd, 4 consecutive tokens per 8B store
#pragma unroll
      for (int m = 0; m < 4; ++m) {
        int row0 = m0 + wr + m * 16 + lg * 4;
        int b2 = row0 >> 11, ns = row0 & 2047;
        ushort4 pk;
        pk.x = f2bf(acc[m][n][0] + bv);
        pk.y = f2bf(acc[m][n][1] + bv);
        pk.z = f2bf(acc[m][n][2] + bv);
        pk.w = f2bf(acc[m][n][3] + bv);
        *(ushort4*)&V[((size_t)(b2 * 12 + h) * 64 + dd) * 2048 + ns] = pk;
      }
    } else {
      u16* dst = (three == 0) ? Q : K;
      float sc = (three == 0) ? 0.125f * 1.44269504f : 1.0f;  // fold log2(e) into Q
#pragma unroll
      for (int m = 0; m < 4; ++m) {
        int row0 = m0 + wr + m * 16 + lg * 4;
#pragma unroll
        for (int j = 0; j < 4; ++j) {
          int row = row0 + j;
          int b2 = row >> 11, ns = row & 2047;
          float val = (acc[m][n][j] + bv) * sc;
          dst[(((b2 * 12 + h) * 2048 + ns) << 6) + dd] = f2bf(val);
        }
      }
    }
  }
}

// ---------------- flash attention v9b: in-register P, LDS-staged K/V, exp2 ------
// 128 q-rows/block (32/wave), KVBLK=64. Swapped QK^T: lane (lr,lg) holds
// S[q=lr][kv=nt*16+lg*4+j]. PV contraction re-ordered (kk = lg*8+(nt&1)*4+j) so
// the P A-fragment is already lane-local: pure casts, no LDS, no shuffles.
// V B-fragment reads the matching kv-split as 2x ds_read_b64.
__global__ __launch_bounds__(256, 4) void attn_kernel(
    const u16* __restrict__ Q, const u16* __restrict__ K,
    const u16* __restrict__ Vt, u16* __restrict__ O) {
  __shared__ u16 Ks[2][64 * 64];   // [kv][d] rows 128B, chunk^swz8(row)
  __shared__ u16 Vs[2][64 * 64];   // [d][kv] rows 128B, chunk^swz8(row)
  const int tid = threadIdx.x, w = tid >> 6, l = tid & 63;
  const int lr = l & 15, lg = l >> 4;
  int d0i = blockIdx.x;
  int bi = (d0i & 7) * 96 + (d0i >> 3);          // XCD swizzle: 6 heads per XCD
  int qt = bi & 15, h = (bi >> 4) % 12, b = bi / 192;
  const u16* Qp = Q + ((size_t)(b * 12 + h) * 2048 + qt * 128) * 64;
  const u16* Kp = K + (size_t)(b * 12 + h) * 2048 * 64;
  const u16* Vp = Vt + (size_t)(b * 12 + h) * 64 * 2048;   // [d][n]
  u16* Op = O + (size_t)(b * 2048 + qt * 128) * 768 + h * 64;

  // Q fragments (B-operand: col=lr <-> q-row)
  bf16x8 aq[2][2];
#pragma unroll
  for (int mt = 0; mt < 2; ++mt)
#pragma unroll
    for (int ks = 0; ks < 2; ++ks)
      aq[mt][ks] = *(const bf16x8*)&Qp[(w * 32 + mt * 16 + lr) * 64 + ks * 32 + lg * 8];

  f32x4 aO[2][4] = {};
  float Mx[2] = {-1e30f, -1e30f};
  float rsum[2] = {0.0f, 0.0f};

#define STAGE(buf, kt)                                                         \
  do {                                                                         \
    const u16* Kt = Kp + (kt) * 4096;                                          \
    const u16* Vg = Vp + (kt) * 64;                                            \
    _Pragma("unroll") for (int i = 0; i < 2; ++i) {                            \
      int c = i * 256 + tid;                                                   \
      int r = c >> 3, q = c & 7;                                               \
      int qs = (q ^ swz8(r)) << 3;                                             \
      gload16(Kt + r * 64 + qs, (char*)Ks[buf] + c * 16);                      \
      gload16(Vg + r * 2048 + qs, (char*)Vs[buf] + c * 16);                    \
    }                                                                          \
  } while (0)

  STAGE(0, 0);
  __syncthreads();

  for (int kt = 0; kt < 32; ++kt) {
    const int p = kt & 1;
    if (kt < 31) STAGE(p ^ 1, kt + 1);          // prefetch: full iter of cover

    // ---- S^T = K·Q^T from Ks[p] ----
    f32x4 S[2][4] = {};
    __builtin_amdgcn_s_setprio(1);
#pragma unroll
    for (int nt = 0; nt < 4; ++nt) {
      int row = nt * 16 + lr;
      int sw = swz8(row);
#pragma unroll
      for (int ks = 0; ks < 2; ++ks) {
        bf16x8 a = *(const bf16x8*)((char*)Ks[p] + row * 128 +
                                    (((ks * 4 + lg) ^ sw) << 4));
        S[0][nt] = mfma16(a, aq[0][ks], S[0][nt]);
        S[1][nt] = mfma16(a, aq[1][ks], S[1][nt]);
      }
    }
    __builtin_amdgcn_s_setprio(0);

    // ---- softmax: p = 2^(S - Mx), P kept fully in registers ----
    bf16x8 ap[2][2];
#pragma unroll
    for (int mt = 0; mt < 2; ++mt) {
      float pmax = S[mt][0][0];
#pragma unroll
      for (int nt = 0; nt < 4; ++nt)
#pragma unroll
        for (int j = 0; j < 4; ++j) pmax = fmaxf(pmax, S[mt][nt][j]);
      if (!__all(pmax - Mx[mt] <= 11.0f)) {   // rare: full reduce + rescale
        float rm = fmaxf(pmax, __shfl_xor(pmax, 16));
        rm = fmaxf(rm, __shfl_xor(rm, 32));
        float mnew = fmaxf(Mx[mt], rm);
        float sc = fexp2(Mx[mt] - mnew);
        Mx[mt] = mnew;
        rsum[mt] *= sc;
        f32x4 scv;
#pragma unroll
        for (int j = 0; j < 4; ++j) scv[j] = __shfl(sc, lg * 4 + j, 16);
#pragma unroll
        for (int dt = 0; dt < 4; ++dt) aO[mt][dt] *= scv;
      }
      float m = Mx[mt];
      f32x4 pe[4];
      float ts = 0.0f;
#pragma unroll
      for (int nt = 0; nt < 4; ++nt) {
#pragma unroll
        for (int j = 0; j < 4; ++j) pe[nt][j] = fexp2(S[mt][nt][j] - m);
        ts += (pe[nt][0] + pe[nt][1]) + (pe[nt][2] + pe[nt][3]);
      }
      rsum[mt] += ts;
      // A-frag: kk = lg*8 + (nt&1)*4 + j  -> [nt=2ks | nt=2ks+1] per MFMA ks
#pragma unroll
      for (int ks = 0; ks < 2; ++ks) {
        bf16x8 f;
#pragma unroll
        for (int j = 0; j < 4; ++j) {
          f[j]     = (__bf16)pe[2 * ks][j];
          f[4 + j] = (__bf16)pe[2 * ks + 1][j];
        }
        ap[mt][ks] = f;
      }
    }

    // ---- O += P·V ; V B-frag matches re-ordered kk: kv = ks*32 + (i>=4)*16 + lg*4 + (i&3)
    __builtin_amdgcn_s_setprio(1);
#pragma unroll
    for (int ks = 0; ks < 2; ++ks)
#pragma unroll
      for (int dt = 0; dt < 4; ++dt) {
        int row = dt * 16 + lr;
        int sw = swz8(row);
        char* vrow = (char*)Vs[p] + row * 128 + (lg & 1) * 8;
        bf16x4 lo = *(const bf16x4*)(vrow + (((ks * 4 + (lg >> 1)) ^ sw) << 4));
        bf16x4 hi = *(const bf16x4*)(vrow + (((ks * 4 + 2 + (lg >> 1)) ^ sw) << 4));
        bf16x8 bv = __builtin_shufflevector(lo, hi, 0, 1, 2, 3, 4, 5, 6, 7);
        aO[0][dt] = mfma16(ap[0][ks], bv, aO[0][dt]);
        aO[1][dt] = mfma16(ap[1][ks], bv, aO[1][dt]);
      }
    __builtin_amdgcn_s_setprio(0);

    __syncthreads();   // drains prefetch (had whole iter), guards dbuf WAR
  }

  // L: combine the 4 lane-group partials (lanes sharing lr)
#pragma unroll
  for (int mt = 0; mt < 2; ++mt) {
    rsum[mt] += __shfl_xor(rsum[mt], 16);
    rsum[mt] += __shfl_xor(rsum[mt], 32);
  }
  // epilogue: row (lg*4+j)'s L fetched from lr-space via shfl
#pragma unroll
  for (int mt = 0; mt < 2; ++mt) {
    float rinv[4];
#pragma unroll
    for (int j = 0; j < 4; ++j) rinv[j] = 1.0f / __shfl(rsum[mt], lg * 4 + j, 16);
#pragma unroll
    for (int dt = 0; dt < 4; ++dt)
#pragma unroll
      for (int j = 0; j < 4; ++j) {
        int row = w * 32 + mt * 16 + lg * 4 + j;
        Op[(size_t)row * 768 + dt * 16 + lr] = f2bf(aO[mt][dt][j] * rinv[j]);
      }
  }
}

// ---------------- out GEMM: C(8192x768) = Ob(8192x768) * Wout^T + b, fp32 out ----------------
__global__ __launch_bounds__(256) void gemm_out(
    const u16* __restrict__ A, const u16* __restrict__ Bm,
    const float* __restrict__ bias, float* __restrict__ C) {
  __shared__ u16 As[128 * 32];
  __shared__ u16 Bs[128 * 32];
  const int tid = threadIdx.x, w = tid >> 6, l = tid & 63;
  const int lr = l & 15, lg = l >> 4;
  const int n0 = blockIdx.x * 128, m0 = blockIdx.y * 128;
  const int wr = (w >> 1) * 64, wc = (w & 1) * 64;
  f32x4 acc[4][4] = {};
  for (int kt = 0; kt < 768; kt += 32) {
    __syncthreads();
    const u16* Ab = A + m0 * 768 + kt;
    const u16* Bb = Bm + n0 * 768 + kt;
#pragma unroll
    for (int i = 0; i < 2; ++i) {
      int c = (i * 4 + w) * 64 + l;
      gload16(Ab + (c >> 2) * 768 + (c & 3) * 8, (char*)As + c * 16);
      gload16(Bb + (c >> 2) * 768 + (c & 3) * 8, (char*)Bs + c * 16);
    }
    __syncthreads();
    bf16x8 af[4], bfr[4];
#pragma unroll
    for (int m = 0; m < 4; ++m)
      af[m] = *(const bf16x8*)&As[(wr + m * 16 + lr) * 32 + lg * 8];
#pragma unroll
    for (int n = 0; n < 4; ++n)
      bfr[n] = *(const bf16x8*)&Bs[(wc + n * 16 + lr) * 32 + lg * 8];
#pragma unroll
    for (int m = 0; m < 4; ++m)
#pragma unroll
      for (int n = 0; n < 4; ++n) acc[m][n] = mfma16(af[m], bfr[n], acc[m][n]);
  }
#pragma unroll
  for (int n = 0; n < 4; ++n) {
    int f = n0 + wc + n * 16 + lr;
    float bv = bias[f];
#pragma unroll
    for (int m = 0; m < 4; ++m) {
      int row0 = m0 + wr + m * 16 + lg * 4;
#pragma unroll
      for (int j = 0; j < 4; ++j) {
        int row = row0 + j;
        C[(size_t)row * 768 + f] = acc[m][n][j] + bv;
      }
    }
  }
}

extern "C" void kernel_launch(void* const* d_in, const int* in_sizes, int n_in,
                              void* d_out, int out_size, void* d_ws, size_t ws_size,
                              hipStream_t stream) {
  const float* x     = (const float*)d_in[0];
  const float* w_qkv = (const float*)d_in[1];
  const float* b_qkv = (const float*)d_in[2];
  const float* w_out = (const float*)d_in[3];
  const float* b_out = (const float*)d_in[4];

  char* ws = (char*)d_ws;
  u16* xb    = (u16*)(ws + 0);
  u16* wqkvb = (u16*)(ws + 12582912);
  u16* wob   = (u16*)(ws + 16121856);
  u16* qb    = (u16*)(ws + 17301504);
  u16* kb    = (u16*)(ws + 29884416);
  u16* vb    = (u16*)(ws + 42467328);   // V^T [b,h,d,n]
  u16* ob    = (u16*)(ws + 55050240);

  cast_bf16<<<786432 / 256, 256, 0, stream>>>(x, xb, 786432);
  cast_bf16<<<221184 / 256, 256, 0, stream>>>(w_qkv, wqkvb, 221184);
  cast_bf16<<<73728 / 256, 256, 0, stream>>>(w_out, wob, 73728);

  gemm_qkv<<<dim3(18, 64), 256, 0, stream>>>(xb, wqkvb, b_qkv, qb, kb, vb);
  attn_kernel<<<768, 256, 0, stream>>>(qb, kb, vb, ob);
  gemm_out<<<dim3(6, 64), 256, 0, stream>>>(ob, wob, b_out, (float*)d_out);
}